// Round 15
// baseline (118.138 us; speedup 1.0000x reference)
//
#include <hip/hip_runtime.h>

// QKBmm: out[b,m,q,kv] = sum_h q[b,m,q,h] * k[b,m,kv,h]
// B=2, M=16, QT=1024, KVT=4096, H=128. fp32 in/out, bf16 MFMA compute.
// Write-bound: 512 MB out; inputs L2/L3-resident. Pure-write ceiling 6.7TB/s.
// R6 WIN (4 blk/CU). R8 neutral. R9 FAILED (tiny phases). R10 FAILED (plain).
// R11 WIN 118.7 (32x32 MFMA full-line NT). R12 FAILED (sc1). R13 FAILED
// (wide tile). R14 NULL (latency hiding) -> phases not load-latency-bound.
// R15: persistent-row blocks. 512 blocks (all resident, 2/CU), each owns
//     64 q-rows x full KVT of one bm. 32 steps; per step: B 128x128 dbuf'd
//     in LDS, 16 MFMAs/wave, 32 full-line NT stores, next-B loads at top,
//     ONE barrier + counted vmcnt(32) (stores NEVER drained in-loop).
//     Writes flow continuously for the block's whole life -> duty cycle ~1.
//     Dual-parity acc so zeroing never waits on in-flight store sources.

#define QT   1024
#define KVT  4096
#define HD   128

using bf16x8 = __attribute__((ext_vector_type(8))) __bf16;
using bf16x4 = __attribute__((ext_vector_type(4))) __bf16;
using f32x16 = __attribute__((ext_vector_type(16))) float;

__global__ __launch_bounds__(256, 2)
void QKBmm_74062416052397_kernel(const float* __restrict__ q,
                                 const float* __restrict__ k,
                                 float* __restrict__ out) {
    __shared__ __bf16 As[64 * 128];        // 16 KB, staged once
    __shared__ __bf16 Bs[2][128 * 128];    // 2 x 32 KB, per-step double buffer

    const int t = threadIdx.x;             // 0..255
    const int b = blockIdx.x;              // 0..511

    // Same-bm blocks land on the same XCD (dispatch round-robins b%8):
    // XCD x serves bm 4x..4x+3; B-panel step-window (4 x 64KB) L2-resident.
    const int xcd = b & 7, idx = b >> 3;   // idx 0..63
    const int bm  = xcd * 4 + (idx >> 4);
    const int m0  = (idx & 15) * 64;

    const float4* __restrict__ Q4 =
        reinterpret_cast<const float4*>(q + ((size_t)bm * QT + m0) * HD);
    const float4* __restrict__ K4 =
        reinterpret_cast<const float4*>(k + (size_t)bm * KVT * HD);
    float* __restrict__ Cp = out + (size_t)bm * QT * KVT;

    const int lane = t & 63;
    const int wid  = t >> 6;
    const int wm   = (wid >> 1) * 32;      // wave rows (2x2 waves of 32x64)
    const int wn   = (wid & 1) * 64;       // wave cols within 128-col step
    const int l31  = lane & 31;
    const int kh   = (lane >> 5) * 8;

    f32x16 accA[2], accB[2];               // dual parity: store-source decoupling
    float4 bv[16];                         // next-step B transit (64 VGPR)

    // ---- Prologue: issue B(0) loads, stage A, then stage B(0) ----
#pragma unroll
    for (int it = 0; it < 16; ++it) {
        int f = it * 256 + t, r = f >> 5, c = f & 31;
        bv[it] = K4[r * 32 + c];
    }
#pragma unroll
    for (int rd = 0; rd < 2; ++rd) {
        float4 av[4];
#pragma unroll
        for (int j = 0; j < 4; ++j) {
            int f = (rd * 4 + j) * 256 + t, r = f >> 5, c = f & 31;
            av[j] = Q4[r * 32 + c];
        }
#pragma unroll
        for (int j = 0; j < 4; ++j) {
            int f = (rd * 4 + j) * 256 + t, r = f >> 5, c = f & 31;
            int e = (r * 128 + c * 4) ^ ((r & 7) << 3);
            *reinterpret_cast<bf16x4*>(&As[e]) =
                bf16x4{ (__bf16)av[j].x, (__bf16)av[j].y,
                        (__bf16)av[j].z, (__bf16)av[j].w };
        }
    }
    asm volatile("s_waitcnt vmcnt(0)" ::: "memory");
#pragma unroll
    for (int it = 0; it < 16; ++it) {
        int f = it * 256 + t, r = f >> 5, c = f & 31;
        int e = (r * 128 + c * 4) ^ ((r & 7) << 3);
        *reinterpret_cast<bf16x4*>(&Bs[0][e]) =
            bf16x4{ (__bf16)bv[it].x, (__bf16)bv[it].y,
                    (__bf16)bv[it].z, (__bf16)bv[it].w };
    }
    asm volatile("s_waitcnt lgkmcnt(0)" ::: "memory");
    __builtin_amdgcn_s_barrier();

    // Per step S (CUR = S&1, static): compute from Bs[CUR]; issue loads for
    // S+1 at top; stores stay in flight across the barrier (vmcnt(32) counts:
    // after it, outstanding <= 32 = exactly this step's stores).
#define BODY(S, CUR, ACC)                                                      \
    {                                                                          \
        if ((S) + 1 < 32) {                                                    \
            const int nrow = ((S) + 1) * 128;                                  \
            _Pragma("unroll")                                                  \
            for (int it = 0; it < 16; ++it) {                                  \
                int f = it * 256 + t, r = f >> 5, c = f & 31;                  \
                bv[it] = K4[(nrow + r) * 32 + c];                              \
            }                                                                  \
        }                                                                      \
        ACC[0] = f32x16{};                                                     \
        ACC[1] = f32x16{};                                                     \
        _Pragma("unroll")                                                      \
        for (int ks = 0; ks < 8; ++ks) {                                       \
            const int kcol = ks * 16 + kh;                                     \
            int ra = wm + l31;                                                 \
            int ea = (ra * 128 + kcol) ^ ((ra & 7) << 3);                      \
            bf16x8 af = *reinterpret_cast<const bf16x8*>(&As[ea]);             \
            _Pragma("unroll")                                                  \
            for (int ni = 0; ni < 2; ++ni) {                                   \
                int rb = wn + ni * 32 + l31;                                   \
                int eb = (rb * 128 + kcol) ^ ((rb & 7) << 3);                  \
                bf16x8 bfr = *reinterpret_cast<const bf16x8*>(&Bs[CUR][eb]);   \
                ACC[ni] = __builtin_amdgcn_mfma_f32_32x32x16_bf16(             \
                    af, bfr, ACC[ni], 0, 0, 0);                                \
            }                                                                  \
        }                                                                      \
        _Pragma("unroll")                                                      \
        for (int ni = 0; ni < 2; ++ni) {                                       \
            _Pragma("unroll")                                                  \
            for (int r = 0; r < 16; ++r) {                                     \
                int row = m0 + wm + (r & 3) + 8 * (r >> 2) + 4 * (lane >> 5);  \
                float* rp = Cp + (size_t)row * KVT + (S) * 128                 \
                            + wn + ni * 32 + l31;                              \
                __builtin_nontemporal_store(ACC[ni][r], rp);                   \
            }                                                                  \
        }                                                                      \
        if ((S) + 1 < 32) {                                                    \
            asm volatile("s_waitcnt vmcnt(32)" ::: "memory");                  \
            _Pragma("unroll")                                                  \
            for (int it = 0; it < 16; ++it) {                                  \
                int f = it * 256 + t, r = f >> 5, c = f & 31;                  \
                int e = (r * 128 + c * 4) ^ ((r & 7) << 3);                    \
                *reinterpret_cast<bf16x4*>(&Bs[CUR ^ 1][e]) =                  \
                    bf16x4{ (__bf16)bv[it].x, (__bf16)bv[it].y,                \
                            (__bf16)bv[it].z, (__bf16)bv[it].w };              \
            }                                                                  \
            asm volatile("s_waitcnt lgkmcnt(0)" ::: "memory");                 \
        }                                                                      \
        __builtin_amdgcn_s_barrier();                                          \
    }

    for (int ss = 0; ss < 16; ++ss) {
        const int s0 = 2 * ss;
        BODY(s0,     0, accA);
        BODY(s0 + 1, 1, accB);
    }
#undef BODY
}

extern "C" void kernel_launch(void* const* d_in, const int* in_sizes, int n_in,
                              void* d_out, int out_size, void* d_ws, size_t ws_size,
                              hipStream_t stream) {
    const float* q = (const float*)d_in[0];
    const float* k = (const float*)d_in[1];
    float* out = (float*)d_out;

    QKBmm_74062416052397_kernel<<<dim3(512), dim3(256), 0, stream>>>(q, k, out);
}